// Round 1
// baseline (148.140 us; speedup 1.0000x reference)
//
#include <hip/hip_runtime.h>
#include <stdint.h>

#define NUM_BBOX    2
#define NUM_CLASSES 20
#define NUM_GRID    7
#define BATCH       64
#define NCELL  (BATCH * NUM_GRID * NUM_GRID)   // 3136
#define NCAND  (NCELL * NUM_BBOX)              // 6272
#define NGROUP (BATCH * NUM_CLASSES)           // 1280
#define MAXG   98
#define NPAD   8192

// ---- workspace layout (bytes) ----
#define WS_SCORE     0         // f32[6272]            25088
#define WS_CELLBOX   25088     // f32[3136*4]          50176
#define WS_CELLLAB   75264     // f32[3136]            12544
#define WS_KEYS      87808     // u64[6272]            50176
#define WS_GCNT      137984    // u32[1280]             5120
#define WS_MEMBERS   143104    // u16[1280*98]        250880 (padded to 250944)
#define WS_KEEP      394048    // f32[6272]            25088
// total ~419 KB

// monotone float -> sortable u32 (ascending float == ascending u32)
__device__ __forceinline__ unsigned fkey(float f) {
    unsigned u = __float_as_uint(f);
    return (u & 0x80000000u) ? ~u : (u | 0x80000000u);
}

__global__ void k_decode(const float* __restrict__ in,
                         float* __restrict__ score,
                         float* __restrict__ cellBox,
                         float* __restrict__ cellLabel,
                         unsigned long long* __restrict__ keys,
                         unsigned* __restrict__ groupCnt,
                         unsigned short* __restrict__ members,
                         float* __restrict__ keepOrig) {
    int cell = blockIdx.x * blockDim.x + threadIdx.x;
    if (cell >= NCELL) return;
    const float* p = in + cell * (NUM_BBOX * (5 + NUM_CLASSES));
    int b  = cell / (NUM_GRID * NUM_GRID);
    int rc = cell % (NUM_GRID * NUM_GRID);
    int r = rc / NUM_GRID, c = rc % NUM_GRID;

    // per-bbox score = max_cls (prob*conf)  -- mul then max, matching reference
    float sc[NUM_BBOX];
    for (int bb = 0; bb < NUM_BBOX; ++bb) {
        const float* q = p + bb * 25;
        float conf = q[4];
        float m = __fmul_rn(q[5], conf);
        for (int k = 1; k < NUM_CLASSES; ++k)
            m = fmaxf(m, __fmul_rn(q[5 + k], conf));
        sc[bb] = m;
    }
    int best = (sc[1] > sc[0]) ? 1 : 0;   // first-occurrence argmax over 2
    const float* q = p + best * 25;

    // label = argmax over classes (first occurrence) + 1
    int lab = 0; float bv = q[5];
    for (int k = 1; k < NUM_CLASSES; ++k)
        if (q[5 + k] > bv) { bv = q[5 + k]; lab = k; }

    // box: x uses row index, y uses col index (as in reference)
    float x  = __fdiv_rn(__fadd_rn(q[0], (float)r), 7.0f);
    float y  = __fdiv_rn(__fadd_rn(q[1], (float)c), 7.0f);
    float hw = __fmul_rn(q[2], 0.5f);
    float hh = __fmul_rn(q[3], 0.5f);
    float x1 = __fsub_rn(x, hw), y1 = __fsub_rn(y, hh);
    float x2 = __fadd_rn(x, hw), y2 = __fadd_rn(y, hh);

    cellBox[cell * 4 + 0] = x1;
    cellBox[cell * 4 + 1] = y1;
    cellBox[cell * 4 + 2] = x2;
    cellBox[cell * 4 + 3] = y2;
    cellLabel[cell] = (float)(lab + 1);

    for (int bb = 0; bb < NUM_BBOX; ++bb) {
        int idx = cell * NUM_BBOX + bb;
        score[idx] = sc[bb];
        keepOrig[idx] = 0.0f;
        bool valid = sc[bb] > 0.5f;
        float kf = valid ? -sc[bb] : __builtin_inff();
        keys[idx] = ((unsigned long long)fkey(kf) << 32) | (unsigned)idx;
        if (valid) {
            int g = b * NUM_CLASSES + lab;
            unsigned slot = atomicAdd(&groupCnt[g], 1u);
            if (slot < MAXG) members[g * MAXG + slot] = (unsigned short)idx;
        }
    }
}

// one thread per (batch,label) group; greedy NMS in global-sorted order
__global__ void k_nms(const unsigned* __restrict__ groupCnt,
                      const unsigned short* __restrict__ members,
                      const unsigned long long* __restrict__ keys,
                      const float* __restrict__ cellBox,
                      float* __restrict__ keepOrig) {
    int g = blockIdx.x * blockDim.x + threadIdx.x;
    if (g >= NGROUP) return;
    int n = (int)groupCnt[g];
    if (n > MAXG) n = MAXG;
    if (n == 0) return;

    unsigned long long k[MAXG];
    for (int i = 0; i < n; ++i) k[i] = keys[members[g * MAXG + i]];
    // insertion sort ascending (== global sorted order restricted to group)
    for (int i = 1; i < n; ++i) {
        unsigned long long v = k[i]; int j = i - 1;
        while (j >= 0 && k[j] > v) { k[j + 1] = k[j]; --j; }
        k[j + 1] = v;
    }

    float4 kept[MAXG]; int nk = 0;
    for (int i = 0; i < n; ++i) {
        int idx  = (int)(unsigned)k[i];
        int cell = idx >> 1;
        float4 bx = *(const float4*)(cellBox + cell * 4);
        bool sup = false;
        for (int t = 0; t < nk && !sup; ++t) {
            float4 a = kept[t];
            float xx1 = fmaxf(a.x, bx.x), yy1 = fmaxf(a.y, bx.y);
            float xx2 = fminf(a.z, bx.z), yy2 = fminf(a.w, bx.w);
            float w = fmaxf(__fsub_rn(xx2, xx1), 0.0f);
            float h = fmaxf(__fsub_rn(yy2, yy1), 0.0f);
            float inter = __fmul_rn(w, h);
            float aa = __fmul_rn(__fsub_rn(a.z, a.x), __fsub_rn(a.w, a.y));
            float ab = __fmul_rn(__fsub_rn(bx.z, bx.x), __fsub_rn(bx.w, bx.y));
            float denom = __fadd_rn(__fsub_rn(__fadd_rn(aa, ab), inter), 1e-9f);
            float iou = __fdiv_rn(inter, denom);
            if (iou > 0.3f) sup = true;
        }
        if (!sup) { kept[nk++] = bx; keepOrig[idx] = 1.0f; }
    }
}

// single-block bitonic sort of u64 keys (stable via idx in low bits) + scatter
__global__ void __launch_bounds__(1024) k_sort(
        const unsigned long long* __restrict__ keys,
        const float* __restrict__ score,
        const float* __restrict__ cellBox,
        const float* __restrict__ cellLabel,
        const float* __restrict__ keepOrig,
        float* __restrict__ out) {
    __shared__ unsigned long long s[NPAD];
    int tid = threadIdx.x;
    for (int i = tid; i < NPAD; i += 1024)
        s[i] = (i < NCAND) ? keys[i] : 0xFFFFFFFFFFFFFFFFull;
    __syncthreads();

    for (unsigned k = 2; k <= NPAD; k <<= 1) {
        for (unsigned j = k >> 1; j > 0; j >>= 1) {
            for (unsigned i = tid; i < NPAD; i += 1024) {
                unsigned ixj = i ^ j;
                if (ixj > i) {
                    unsigned long long a = s[i], b = s[ixj];
                    bool up = ((i & k) == 0);
                    if ((a > b) == up) { s[i] = b; s[ixj] = a; }
                }
            }
            __syncthreads();
        }
    }

    float* out_ids  = out;
    float* out_box  = out + NCAND;
    float* out_lab  = out + NCAND * 5;
    float* out_sco  = out + NCAND * 6;
    float* out_keep = out + NCAND * 7;
    for (int jj = tid; jj < NCAND; jj += 1024) {
        unsigned idx = (unsigned)s[jj];
        int cell = (int)(idx >> 1);
        out_ids[jj] = (float)(idx / 98u);
        float4 bx = *(const float4*)(cellBox + cell * 4);
        *(float4*)(out_box + jj * 4) = bx;
        out_lab[jj]  = cellLabel[cell];
        out_sco[jj]  = score[idx];
        out_keep[jj] = keepOrig[idx];
    }
}

extern "C" void kernel_launch(void* const* d_in, const int* in_sizes, int n_in,
                              void* d_out, int out_size, void* d_ws, size_t ws_size,
                              hipStream_t stream) {
    const float* in = (const float*)d_in[0];
    char* ws = (char*)d_ws;
    float*              score     = (float*)(ws + WS_SCORE);
    float*              cellBox   = (float*)(ws + WS_CELLBOX);
    float*              cellLabel = (float*)(ws + WS_CELLLAB);
    unsigned long long* keys      = (unsigned long long*)(ws + WS_KEYS);
    unsigned*           groupCnt  = (unsigned*)(ws + WS_GCNT);
    unsigned short*     members   = (unsigned short*)(ws + WS_MEMBERS);
    float*              keepOrig  = (float*)(ws + WS_KEEP);
    float* out = (float*)d_out;

    hipMemsetAsync(groupCnt, 0, NGROUP * sizeof(unsigned), stream);
    k_decode<<<(NCELL + 63) / 64, 64, 0, stream>>>(in, score, cellBox, cellLabel,
                                                   keys, groupCnt, members, keepOrig);
    k_nms<<<(NGROUP + 63) / 64, 64, 0, stream>>>(groupCnt, members, keys, cellBox, keepOrig);
    k_sort<<<1, 1024, 0, stream>>>(keys, score, cellBox, cellLabel, keepOrig, out);
}

// Round 2
// 55.664 us; speedup vs baseline: 2.6613x; 2.6613x over previous
//
#include <hip/hip_runtime.h>
#include <stdint.h>

#define NUM_BBOX    2
#define NUM_CLASSES 20
#define NUM_GRID    7
#define BATCH       64
#define NCELL  (BATCH * NUM_GRID * NUM_GRID)   // 3136
#define NCAND  (NCELL * NUM_BBOX)              // 6272
#define NGROUP (BATCH * NUM_CLASSES)           // 1280
#define MAXG   98
#define NJT    8
#define JTILE  (NCAND / NJT)                   // 784

// ---- workspace layout (bytes) ----
#define WS_SCORE     0         // f32[6272]            25088
#define WS_CELLBOX   25088     // f32[3136*4]          50176
#define WS_CELLLAB   75264     // f32[3136]            12544
#define WS_KEYS      87808     // u64[6272]            50176
#define WS_GCNT      137984    // u32[1280]             5120
#define WS_MEMBERS   143104    // u16[1280*98]        250880 (padded to 250944)
#define WS_KEEP      394048    // f32[6272]            25088
#define WS_RANK      419136    // u32[6272]            25088
// total ~445 KB

// monotone float -> sortable u32 (ascending float == ascending u32)
__device__ __forceinline__ unsigned fkey(float f) {
    unsigned u = __float_as_uint(f);
    return (u & 0x80000000u) ? ~u : (u | 0x80000000u);
}

__global__ void k_decode(const float* __restrict__ in,
                         float* __restrict__ score,
                         float* __restrict__ cellBox,
                         float* __restrict__ cellLabel,
                         unsigned long long* __restrict__ keys,
                         unsigned* __restrict__ groupCnt,
                         unsigned short* __restrict__ members,
                         float* __restrict__ keepOrig,
                         unsigned* __restrict__ rank) {
    int cell = blockIdx.x * blockDim.x + threadIdx.x;
    if (cell >= NCELL) return;
    const float* p = in + cell * (NUM_BBOX * (5 + NUM_CLASSES));
    int b  = cell / (NUM_GRID * NUM_GRID);
    int rc = cell % (NUM_GRID * NUM_GRID);
    int r = rc / NUM_GRID, c = rc % NUM_GRID;

    // per-bbox score = max_cls (prob*conf)  -- mul then max, matching reference
    float sc[NUM_BBOX];
    for (int bb = 0; bb < NUM_BBOX; ++bb) {
        const float* q = p + bb * 25;
        float conf = q[4];
        float m = __fmul_rn(q[5], conf);
        for (int k = 1; k < NUM_CLASSES; ++k)
            m = fmaxf(m, __fmul_rn(q[5 + k], conf));
        sc[bb] = m;
    }
    int best = (sc[1] > sc[0]) ? 1 : 0;   // first-occurrence argmax over 2
    const float* q = p + best * 25;

    // label = argmax over classes (first occurrence) + 1
    int lab = 0; float bv = q[5];
    for (int k = 1; k < NUM_CLASSES; ++k)
        if (q[5 + k] > bv) { bv = q[5 + k]; lab = k; }

    // box: x uses row index, y uses col index (as in reference)
    float x  = __fdiv_rn(__fadd_rn(q[0], (float)r), 7.0f);
    float y  = __fdiv_rn(__fadd_rn(q[1], (float)c), 7.0f);
    float hw = __fmul_rn(q[2], 0.5f);
    float hh = __fmul_rn(q[3], 0.5f);
    float x1 = __fsub_rn(x, hw), y1 = __fsub_rn(y, hh);
    float x2 = __fadd_rn(x, hw), y2 = __fadd_rn(y, hh);

    cellBox[cell * 4 + 0] = x1;
    cellBox[cell * 4 + 1] = y1;
    cellBox[cell * 4 + 2] = x2;
    cellBox[cell * 4 + 3] = y2;
    cellLabel[cell] = (float)(lab + 1);

    for (int bb = 0; bb < NUM_BBOX; ++bb) {
        int idx = cell * NUM_BBOX + bb;
        score[idx] = sc[bb];
        keepOrig[idx] = 0.0f;
        rank[idx] = 0u;
        bool valid = sc[bb] > 0.5f;
        float kf = valid ? -sc[bb] : __builtin_inff();
        keys[idx] = ((unsigned long long)fkey(kf) << 32) | (unsigned)idx;
        if (valid) {
            int g = b * NUM_CLASSES + lab;
            unsigned slot = atomicAdd(&groupCnt[g], 1u);
            if (slot < MAXG) members[g * MAXG + slot] = (unsigned short)idx;
        }
    }
}

// one thread per (batch,label) group; greedy NMS in global-sorted order
__global__ void k_nms(const unsigned* __restrict__ groupCnt,
                      const unsigned short* __restrict__ members,
                      const unsigned long long* __restrict__ keys,
                      const float* __restrict__ cellBox,
                      float* __restrict__ keepOrig) {
    int g = blockIdx.x * blockDim.x + threadIdx.x;
    if (g >= NGROUP) return;
    int n = (int)groupCnt[g];
    if (n > MAXG) n = MAXG;
    if (n == 0) return;

    unsigned long long k[MAXG];
    for (int i = 0; i < n; ++i) k[i] = keys[members[g * MAXG + i]];
    // insertion sort ascending (== global sorted order restricted to group)
    for (int i = 1; i < n; ++i) {
        unsigned long long v = k[i]; int j = i - 1;
        while (j >= 0 && k[j] > v) { k[j + 1] = k[j]; --j; }
        k[j + 1] = v;
    }

    float4 kept[MAXG]; int nk = 0;
    for (int i = 0; i < n; ++i) {
        int idx  = (int)(unsigned)k[i];
        int cell = idx >> 1;
        float4 bx = *(const float4*)(cellBox + cell * 4);
        bool sup = false;
        for (int t = 0; t < nk && !sup; ++t) {
            float4 a = kept[t];
            float xx1 = fmaxf(a.x, bx.x), yy1 = fmaxf(a.y, bx.y);
            float xx2 = fminf(a.z, bx.z), yy2 = fminf(a.w, bx.w);
            float w = fmaxf(__fsub_rn(xx2, xx1), 0.0f);
            float h = fmaxf(__fsub_rn(yy2, yy1), 0.0f);
            float inter = __fmul_rn(w, h);
            float aa = __fmul_rn(__fsub_rn(a.z, a.x), __fsub_rn(a.w, a.y));
            float ab = __fmul_rn(__fsub_rn(bx.z, bx.x), __fsub_rn(bx.w, bx.y));
            float denom = __fadd_rn(__fsub_rn(__fadd_rn(aa, ab), inter), 1e-9f);
            float iou = __fdiv_rn(inter, denom);
            if (iou > 0.3f) sup = true;
        }
        if (!sup) { kept[nk++] = bx; keepOrig[idx] = 1.0f; }
    }
}

// rank[i] = #{ j : keys[j] < keys[i] }  (keys unique -> bijective rank).
// grid (98 i-blocks, 8 j-tiles) x 64 threads; keys[j] is wave-uniform.
__global__ void __launch_bounds__(64) k_rank(
        const unsigned long long* __restrict__ keys,
        unsigned* __restrict__ rank) {
    int i  = blockIdx.x * 64 + (int)threadIdx.x;
    int j0 = blockIdx.y * JTILE;
    unsigned long long my = keys[i];
    unsigned r = 0;
    #pragma unroll 8
    for (int j = j0; j < j0 + JTILE; ++j)
        r += (keys[j] < my) ? 1u : 0u;
    atomicAdd(&rank[i], r);
}

// write source element i to its sorted position rank[i]
__global__ void __launch_bounds__(64) k_scatter(
        const unsigned* __restrict__ rank,
        const float* __restrict__ score,
        const float* __restrict__ cellBox,
        const float* __restrict__ cellLabel,
        const float* __restrict__ keepOrig,
        float* __restrict__ out) {
    int i = blockIdx.x * 64 + (int)threadIdx.x;
    unsigned r = rank[i];
    int cell = i >> 1;
    // idx = b*98 + (rc*2+bb) with rc*2+bb < 98  ->  i/98 == batch id
    out[r] = (float)(i / 98);
    float4 bx = *(const float4*)(cellBox + cell * 4);
    *(float4*)(out + NCAND + r * 4) = bx;
    out[NCAND * 5 + r] = cellLabel[cell];
    out[NCAND * 6 + r] = score[i];
    out[NCAND * 7 + r] = keepOrig[i];
}

extern "C" void kernel_launch(void* const* d_in, const int* in_sizes, int n_in,
                              void* d_out, int out_size, void* d_ws, size_t ws_size,
                              hipStream_t stream) {
    const float* in = (const float*)d_in[0];
    char* ws = (char*)d_ws;
    float*              score     = (float*)(ws + WS_SCORE);
    float*              cellBox   = (float*)(ws + WS_CELLBOX);
    float*              cellLabel = (float*)(ws + WS_CELLLAB);
    unsigned long long* keys      = (unsigned long long*)(ws + WS_KEYS);
    unsigned*           groupCnt  = (unsigned*)(ws + WS_GCNT);
    unsigned short*     members   = (unsigned short*)(ws + WS_MEMBERS);
    float*              keepOrig  = (float*)(ws + WS_KEEP);
    unsigned*           rank      = (unsigned*)(ws + WS_RANK);
    float* out = (float*)d_out;

    hipMemsetAsync(groupCnt, 0, NGROUP * sizeof(unsigned), stream);
    k_decode<<<(NCELL + 63) / 64, 64, 0, stream>>>(in, score, cellBox, cellLabel,
                                                   keys, groupCnt, members, keepOrig, rank);
    k_nms<<<(NGROUP + 63) / 64, 64, 0, stream>>>(groupCnt, members, keys, cellBox, keepOrig);
    k_rank<<<dim3(NCAND / 64, NJT), 64, 0, stream>>>(keys, rank);
    k_scatter<<<NCAND / 64, 64, 0, stream>>>(rank, score, cellBox, cellLabel, keepOrig, out);
}